// Round 1
// baseline (957.779 us; speedup 1.0000x reference)
//
#include <hip/hip_runtime.h>
#include <hip/hip_fp16.h>

#define N_NODES 25000   // = 3125 * 8 exactly
#define E_EDGES 400000
#define KM 200      // message channels
#define RSA 256     // A-row stride in USHORTS: 200 bf16 A | pad | 20 fp32 x @u208 (512 B row)
#define RSB 256     // B-row stride BYTES: 200 int8 | pad | 20 fp16 x @208 | inv_p,inv_x @248

typedef float v2f __attribute__((ext_vector_type(2)));  // v_pk_fma_f32 operand

__device__ __forceinline__ float2 h2f(unsigned u) {
  return __half22float2(*(const __half2*)&u);
}
__device__ __forceinline__ float4 i8x4f(unsigned u) {
  float4 f;
  f.x = (float)((int)(u << 24) >> 24);
  f.y = (float)((int)(u << 16) >> 24);
  f.z = (float)((int)(u << 8) >> 24);
  f.w = (float)((int)u >> 24);
  return f;
}
// bf16 round-half-up pack / unpack
__device__ __forceinline__ unsigned short f2bfr(float v) {
  unsigned u = __float_as_uint(v) + 0x8000u;
  return (unsigned short)(u >> 16);
}
__device__ __forceinline__ float bf2f(unsigned short h) {
  return __uint_as_float((unsigned)h << 16);
}

// Segment sum with batched loads: bitwise-identical to the naive loop.
__device__ __forceinline__ float seg_sum_bf16(const unsigned short* __restrict__ g,
                                              int s, int t) {
  float v = 0.f;
  int e = s;
  int t8 = s + ((t - s) & ~7);
  for (; e < t8; e += 8) {
    unsigned short u0 = g[e + 0], u1 = g[e + 1], u2 = g[e + 2], u3 = g[e + 3];
    unsigned short u4 = g[e + 4], u5 = g[e + 5], u6 = g[e + 6], u7 = g[e + 7];
    v += bf2f(u0); v += bf2f(u1); v += bf2f(u2); v += bf2f(u3);
    v += bf2f(u4); v += bf2f(u5); v += bf2f(u6); v += bf2f(u7);
  }
  int t2 = s + ((t - s) & ~1);
  for (; e < t2; e += 2) {
    unsigned short u0 = g[e + 0], u1 = g[e + 1];
    v += bf2f(u0); v += bf2f(u1);
  }
  if (e < t) v += bf2f(g[e]);
  return v;
}

// ---------------- sort-by-dst (CSR build) ----------------

__global__ void hist_kernel(const int* __restrict__ edges, int* __restrict__ hist) {
  int e = blockIdx.x * blockDim.x + threadIdx.x;
  if (e < E_EDGES) atomicAdd(&hist[edges[E_EDGES + e]], 1);
}

__global__ void scan_kernel(const int* __restrict__ hist, int* __restrict__ off,
                            int* __restrict__ cursor) {
  __shared__ int sums[1024];
  const int CH = (N_NODES + 1023) / 1024;  // 25
  int tid = threadIdx.x;
  int base = tid * CH;
  int s = 0;
  for (int i = 0; i < CH; i++) {
    int idx = base + i;
    if (idx < N_NODES) s += hist[idx];
  }
  sums[tid] = s;
  __syncthreads();
  for (int d = 1; d < 1024; d <<= 1) {
    int v = (tid >= d) ? sums[tid - d] : 0;
    __syncthreads();
    sums[tid] += v;
    __syncthreads();
  }
  int run = (tid == 0) ? 0 : sums[tid - 1];
  for (int i = 0; i < CH; i++) {
    int idx = base + i;
    if (idx < N_NODES) {
      off[idx] = run;
      cursor[idx] = run;
      run += hist[idx];
    }
  }
  if (tid == 1023) off[N_NODES] = run;  // == E
}

// ---------------- per-layer kernels ----------------

// Fused: scatter (128 edges/block) + prep layer-d (8 nodes/block) + d_out zeroing.
// A-panel now bf16 (halves gather bytes); x-tail fp32 at ushort offset 208.
__global__ void __launch_bounds__(256) scatter_prep_d_kernel(
    const int* __restrict__ edges, int* __restrict__ cursor, int2* __restrict__ se,
    const float* __restrict__ xin,
    const float* __restrict__ Wm1, const float* __restrict__ bm1,
    unsigned short* __restrict__ A2, unsigned char* __restrict__ Bq,
    float* __restrict__ xr, float* __restrict__ out) {
  int tid = threadIdx.x;
  if (tid < 8) out[blockIdx.x * 8 + tid] = 0.f;
  if (tid < 128) {
    int e = blockIdx.x * 128 + tid;
    int s = edges[e];
    int d = edges[E_EDGES + e];
    int pos = atomicAdd(&cursor[d], 1);
    se[pos] = make_int2(s, d);
  }
  __shared__ unsigned wbmaxu;
  if (tid == 0) wbmaxu = 0;
  __syncthreads();
  int k = tid;
  float wa = 0.f, wb = 0.f, bm = 0.f;
  if (k < KM) {
    bm = bm1[k];
    wa = Wm1[k];
    wb = Wm1[KM + k];
  }
  float mb = (k < KM) ? fabsf(wb) : 0.f;
#pragma unroll
  for (int s = 1; s < 64; s <<= 1) mb = fmaxf(mb, __shfl_xor(mb, s));
  if ((k & 63) == 0) atomicMax(&wbmaxu, __float_as_uint(mb));
  __syncthreads();
  float wbmax = fmaxf(__uint_as_float(wbmaxu), 1e-30f);
  int n0 = blockIdx.x * 8;
  for (int i = 0; i < 8; i++) {
    int n = n0 + i;
    float xv = xin[n];
    float bBound = fmaxf(fabsf(xv) * wbmax, 1e-30f);
    float xBound = fmaxf(fabsf(xv), 1e-30f);
    size_t rowA = (size_t)n * RSA;
    unsigned char* rb = Bq + (size_t)n * RSB;
    if (k == 0) {
      xr[n] = xv;
      ((float*)(A2 + rowA + 208))[0] = xv;
      ((__half*)(rb + 208))[0] = __float2half(xv * (32768.f / xBound));
      ((float*)(rb + 248))[0] = bBound / 127.f;
      ((float*)(rb + 248))[1] = xBound / 32768.f;
    }
    if (k < KM) {
      A2[rowA + k] = f2bfr(bm + xv * wa);
      rb[k] = (unsigned char)(signed char)lrintf(xv * wb * (127.f / bBound));
    }
  }
}

// 32-k tile: A = 32 bf16 (4 uint4), B = 32 int8 (2 uint4). k0 must be
// compile-time-uniform so Wm2 reads stay scalar loads.
template <int CIN>
__device__ __forceinline__ void tile32(uint4 ua0, uint4 ua1, uint4 ua2, uint4 ua3,
                                       uint4 ub0, uint4 ub1, float invB,
                                       const float* __restrict__ Wm2, int k0,
                                       v2f* gate2) {
  unsigned au[16] = {ua0.x, ua0.y, ua0.z, ua0.w, ua1.x, ua1.y, ua1.z, ua1.w,
                     ua2.x, ua2.y, ua2.z, ua2.w, ua3.x, ua3.y, ua3.z, ua3.w};
  unsigned bu[8] = {ub0.x, ub0.y, ub0.z, ub0.w, ub1.x, ub1.y, ub1.z, ub1.w};
  float hv[32];
#pragma unroll
  for (int w = 0; w < 8; ++w) {
    float4 fb = i8x4f(bu[w]);
    unsigned a0 = au[2 * w], a1 = au[2 * w + 1];
    hv[4 * w + 0] = fmaxf(__uint_as_float(a0 << 16) + fb.x * invB, 0.f);
    hv[4 * w + 1] = fmaxf(__uint_as_float(a0 & 0xffff0000u) + fb.y * invB, 0.f);
    hv[4 * w + 2] = fmaxf(__uint_as_float(a1 << 16) + fb.z * invB, 0.f);
    hv[4 * w + 3] = fmaxf(__uint_as_float(a1 & 0xffff0000u) + fb.w * invB, 0.f);
  }
  if constexpr (CIN == 20) {
#pragma unroll
    for (int j = 0; j < 32; ++j) {
      v2f hj;
      hj.x = hv[j];
      hj.y = hv[j];
      const v2f* w2 = (const v2f*)(Wm2 + (k0 + j) * 20);
#pragma unroll
      for (int i = 0; i < 10; ++i) gate2[i] += hj * w2[i];
    }
  } else {
    float g = gate2[0].x;
#pragma unroll
    for (int j = 0; j < 32; ++j) g += hv[j] * Wm2[k0 + j];
    gate2[0].x = g;
  }
}

// tail tile: k = 192..199 (8 k): A = 1 uint4 (8 bf16), B = 2 dwords (8 int8)
template <int CIN>
__device__ __forceinline__ void tile8(uint4 ua0, unsigned bw0, unsigned bw1,
                                      float invB, const float* __restrict__ Wm2,
                                      v2f* gate2) {
  unsigned au[4] = {ua0.x, ua0.y, ua0.z, ua0.w};
  unsigned bu[2] = {bw0, bw1};
  float hv[8];
#pragma unroll
  for (int w = 0; w < 2; ++w) {
    float4 fb = i8x4f(bu[w]);
    unsigned a0 = au[2 * w], a1 = au[2 * w + 1];
    hv[4 * w + 0] = fmaxf(__uint_as_float(a0 << 16) + fb.x * invB, 0.f);
    hv[4 * w + 1] = fmaxf(__uint_as_float(a0 & 0xffff0000u) + fb.y * invB, 0.f);
    hv[4 * w + 2] = fmaxf(__uint_as_float(a1 << 16) + fb.z * invB, 0.f);
    hv[4 * w + 3] = fmaxf(__uint_as_float(a1 & 0xffff0000u) + fb.w * invB, 0.f);
  }
  if constexpr (CIN == 20) {
#pragma unroll
    for (int j = 0; j < 8; ++j) {
      v2f hj;
      hj.x = hv[j];
      hj.y = hv[j];
      const v2f* w2 = (const v2f*)(Wm2 + (192 + j) * 20);
#pragma unroll
      for (int i = 0; i < 10; ++i) gate2[i] += hj * w2[i];
    }
  } else {
    float g = gate2[0].x;
#pragma unroll
    for (int j = 0; j < 8; ++j) g += hv[j] * Wm2[192 + j];
    gate2[0].x = g;
  }
}

// Edge kernel: one thread per (dst-sorted) edge, 128-thread blocks.
// Software-pipelined k-loop: prefetch tile t+1 (registers) while computing
// tile t, fully unrolled — hides the scattered-gather latency that the
// profile showed (VALUBusy 48%, 52% stall). A-panel bf16, B int8.
template <int CIN>
__global__ void __launch_bounds__(128) edge_kernel(
    const int2* __restrict__ se,
    const unsigned short* __restrict__ A2, const unsigned char* __restrict__ Bq,
    const float* __restrict__ Wm2, const float* __restrict__ bm2,
    unsigned short* __restrict__ gd) {
  int e = blockIdx.x * 128 + threadIdx.x;  // grid exact: no bounds check
  int2 sd = se[e];
  int src = sd.x;
  int dst = sd.y;
  const unsigned short* Ar = A2 + (size_t)dst * RSA;
  const unsigned char* Br = Bq + (size_t)src * RSB;
  float invB = ((const float*)(Br + 248))[0];
  constexpr int NP = (CIN + 1) / 2;
  v2f gate2[NP];
  if constexpr (CIN == 20) {
#pragma unroll
    for (int i = 0; i < NP; i++) gate2[i] = *(const v2f*)(bm2 + 2 * i);
  } else {
    gate2[0].x = bm2[0];
    gate2[0].y = 0.f;
  }
  // prologue: tile 0
  uint4 ca0 = *(const uint4*)(Ar + 0);
  uint4 ca1 = *(const uint4*)(Ar + 8);
  uint4 ca2 = *(const uint4*)(Ar + 16);
  uint4 ca3 = *(const uint4*)(Ar + 24);
  uint4 cb0 = *(const uint4*)(Br + 0);
  uint4 cb1 = *(const uint4*)(Br + 16);
#pragma unroll
  for (int t = 0; t < 6; ++t) {
    uint4 na0, na1, na2, na3, nb0, nb1;
    if (t < 5) {
      const unsigned short* ap = Ar + 32 * (t + 1);
      na0 = *(const uint4*)(ap + 0);
      na1 = *(const uint4*)(ap + 8);
      na2 = *(const uint4*)(ap + 16);
      na3 = *(const uint4*)(ap + 24);
      const unsigned char* bp = Br + 32 * (t + 1);
      nb0 = *(const uint4*)(bp + 0);
      nb1 = *(const uint4*)(bp + 16);
    } else {  // tail prefetch: 8 k
      na0 = *(const uint4*)(Ar + 192);
      uint2 bt = *(const uint2*)(Br + 192);
      nb0 = make_uint4(bt.x, bt.y, 0, 0);
      na1 = na2 = na3 = nb1 = make_uint4(0, 0, 0, 0);
    }
    tile32<CIN>(ca0, ca1, ca2, ca3, cb0, cb1, invB, Wm2, 32 * t, gate2);
    ca0 = na0; ca1 = na1; ca2 = na2; ca3 = na3; cb0 = nb0; cb1 = nb1;
  }
  tile8<CIN>(ca0, cb0.x, cb0.y, invB, Wm2, gate2);
  // x-diff tails: A-x fp32 @ushort 208, B-x fp16-scaled; coalesced bf16 nt-stores
  float invXb = ((const float*)(Br + 248))[1];
  const __half* xtb = (const __half*)(Br + 208);
  const float* Ax = (const float*)(Ar + 208);
  if constexpr (CIN == 20) {
    unsigned wxb[10];
    {
      uint4 s0 = *(const uint4*)(xtb);
      uint4 s1 = *(const uint4*)(xtb + 8);
      uint2 s2 = *(const uint2*)(xtb + 16);
      wxb[0] = s0.x; wxb[1] = s0.y; wxb[2] = s0.z; wxb[3] = s0.w;
      wxb[4] = s1.x; wxb[5] = s1.y; wxb[6] = s1.z; wxb[7] = s1.w;
      wxb[8] = s2.x; wxb[9] = s2.y;
    }
#pragma unroll
    for (int i = 0; i < 10; i++) {
      float2 xa = *(const float2*)(Ax + 2 * i);
      float2 fb = h2f(wxb[i]);
      int c0 = 2 * i, c1 = 2 * i + 1;
      __builtin_nontemporal_store(f2bfr(gate2[i].x * (xa.x - fb.x * invXb)),
                                  gd + (size_t)c0 * E_EDGES + e);
      __builtin_nontemporal_store(f2bfr(gate2[i].y * (xa.y - fb.y * invXb)),
                                  gd + (size_t)c1 * E_EDGES + e);
    }
  } else {
    float xa = Ax[0];
    float xb = __half2float(xtb[0]) * invXb;
    __builtin_nontemporal_store(f2bfr(gate2[0].x * (xa - xb)), gd + e);
  }
}

// Final-layer edge kernel + node-term fold (same pipelined loop).
__global__ void __launch_bounds__(128) edge_final_kernel(
    const int2* __restrict__ se,
    const unsigned short* __restrict__ A2, const unsigned char* __restrict__ Bq,
    const float* __restrict__ Wm2, const float* __restrict__ bm2,
    const float* __restrict__ W2,
    const int* __restrict__ off, const float* __restrict__ xrp,
    const float* __restrict__ W1, const float* __restrict__ b1,
    const float* __restrict__ b2, float* __restrict__ out) {
  int e = blockIdx.x * 128 + threadIdx.x;
  int2 sd = se[e];
  int src = sd.x;
  int dst = sd.y;
  const unsigned short* Ar = A2 + (size_t)dst * RSA;
  const unsigned char* Br = Bq + (size_t)src * RSB;
  float invB = ((const float*)(Br + 248))[0];
  v2f gate2[10];
#pragma unroll
  for (int i = 0; i < 10; i++) gate2[i] = *(const v2f*)(bm2 + 2 * i);
  uint4 ca0 = *(const uint4*)(Ar + 0);
  uint4 ca1 = *(const uint4*)(Ar + 8);
  uint4 ca2 = *(const uint4*)(Ar + 16);
  uint4 ca3 = *(const uint4*)(Ar + 24);
  uint4 cb0 = *(const uint4*)(Br + 0);
  uint4 cb1 = *(const uint4*)(Br + 16);
#pragma unroll
  for (int t = 0; t < 6; ++t) {
    uint4 na0, na1, na2, na3, nb0, nb1;
    if (t < 5) {
      const unsigned short* ap = Ar + 32 * (t + 1);
      na0 = *(const uint4*)(ap + 0);
      na1 = *(const uint4*)(ap + 8);
      na2 = *(const uint4*)(ap + 16);
      na3 = *(const uint4*)(ap + 24);
      const unsigned char* bp = Br + 32 * (t + 1);
      nb0 = *(const uint4*)(bp + 0);
      nb1 = *(const uint4*)(bp + 16);
    } else {
      na0 = *(const uint4*)(Ar + 192);
      uint2 bt = *(const uint2*)(Br + 192);
      nb0 = make_uint4(bt.x, bt.y, 0, 0);
      na1 = na2 = na3 = nb1 = make_uint4(0, 0, 0, 0);
    }
    tile32<20>(ca0, ca1, ca2, ca3, cb0, cb1, invB, Wm2, 32 * t, gate2);
    ca0 = na0; ca1 = na1; ca2 = na2; ca3 = na3; cb0 = nb0; cb1 = nb1;
  }
  tile8<20>(ca0, cb0.x, cb0.y, invB, Wm2, gate2);
  // scalar edge contribution: dot(gate * xd, W2)
  float invXb = ((const float*)(Br + 248))[1];
  const __half* xtb = (const __half*)(Br + 208);
  const float* Ax = (const float*)(Ar + 208);
  unsigned wxb[10];
  {
    uint4 s0 = *(const uint4*)(xtb);
    uint4 s1 = *(const uint4*)(xtb + 8);
    uint2 s2 = *(const uint2*)(xtb + 16);
    wxb[0] = s0.x; wxb[1] = s0.y; wxb[2] = s0.z; wxb[3] = s0.w;
    wxb[4] = s1.x; wxb[5] = s1.y; wxb[6] = s1.z; wxb[7] = s1.w;
    wxb[8] = s2.x; wxb[9] = s2.y;
  }
  float sv = 0.f;
#pragma unroll
  for (int i = 0; i < 10; i++) {
    float2 xa = *(const float2*)(Ax + 2 * i);
    float2 fb = h2f(wxb[i]);
    sv += gate2[i].x * (xa.x - fb.x * invXb) * W2[2 * i] +
          gate2[i].y * (xa.y - fb.y * invXb) * W2[2 * i + 1];
  }
  // wave-level segmented sum over equal-dst runs (dst-sorted), then 1 atomic/run
  int lane = threadIdx.x & 63;
  bool seg[6];
#pragma unroll
  for (int i = 0; i < 6; i++) {
    int s = 1 << i;
    int od = __shfl_up(dst, s);
    seg[i] = (lane >= s) && (od == dst);
  }
#pragma unroll
  for (int i = 0; i < 6; i++) {
    float o = __shfl_up(sv, 1 << i);
    if (seg[i]) sv += o;
  }
  int dn = __shfl_down(dst, 1);
  bool is_last = (lane == 63) || (dn != dst);
  if (is_last) atomicAdd(out + dst, sv);
  // node-term fold: 8 nodes/block, grid 3125 = N/8
  int tid = threadIdx.x;
  if (tid < 8) {
    int n = blockIdx.x * 8 + tid;
    float deg = (float)(off[n + 1] - off[n]);
    float v = b1[0] + deg * b2[0];
    const float* xp = xrp + (size_t)n * 20;
#pragma unroll
    for (int c = 0; c < 20; c++) v += xp[c] * W1[c];
    atomicAdd(out + n, v);
  }
}

// afp1: after layer-d edge (gd 1-channel bf16). Per block: 8 nodes.
__global__ void __launch_bounds__(256) afp1_kernel(
    const unsigned short* __restrict__ gd, const int* __restrict__ off,
    const float* __restrict__ xrp,
    const float* __restrict__ W1, const float* __restrict__ b1,
    const float* __restrict__ W2, const float* __restrict__ b2,
    const float* __restrict__ Wm1n, const float* __restrict__ bm1n,
    unsigned short* __restrict__ A2, unsigned char* __restrict__ Bq,
    float* __restrict__ xrn) {
  __shared__ float ag[8], xp[8], degs[8];
  __shared__ float xv[8][21];
  __shared__ unsigned bmaxu[8];
  __shared__ float xmaxs[8];
  int tid = threadIdx.x;
  int n0 = blockIdx.x * 8;
  if (tid < 8) {
    bmaxu[tid] = 0;
    int n = n0 + tid;
    int s = off[n], t = off[n + 1];
    ag[tid] = seg_sum_bf16(gd, s, t);
    xp[tid] = xrp[n];
    degs[tid] = (float)(t - s);
  }
  __syncthreads();
  if (tid < 160) {
    int o = tid >> 3, nl = tid & 7;
    float v = b1[o] + degs[nl] * b2[o] + ag[nl] * W2[o] + xp[nl] * W1[o];
    float r = fmaxf(v, 0.f);
    xv[nl][o] = r;
    xrn[(n0 + nl) * 20 + o] = r;
  }
  __syncthreads();
  if (tid < 8) {
    float m = 0.f;
#pragma unroll
    for (int c = 0; c < 20; c++) m = fmaxf(m, xv[tid][c]);
    xmaxs[tid] = fmaxf(m, 1e-30f);
  }
  int k = tid;
  float aa[8], bb[8];
  if (k < KM) {
    v2f wab[20];
    float bm = bm1n[k];
#pragma unroll
    for (int c = 0; c < 20; c++) {
      wab[c].x = Wm1n[c * KM + k];
      wab[c].y = Wm1n[(20 + c) * KM + k];
    }
#pragma unroll
    for (int nl = 0; nl < 8; nl++) {
      v2f acc;
      acc.x = bm;
      acc.y = 0.f;
#pragma unroll
      for (int c = 0; c < 20; c++) {
        v2f xc;
        xc.x = xv[nl][c];
        xc.y = xv[nl][c];
        acc += xc * wab[c];
      }
      aa[nl] = acc.x;
      bb[nl] = acc.y;
    }
  }
  float mxb[8];
#pragma unroll
  for (int nl = 0; nl < 8; nl++) mxb[nl] = (k < KM) ? fabsf(bb[nl]) : 0.f;
#pragma unroll
  for (int s = 1; s < 64; s <<= 1) {
#pragma unroll
    for (int nl = 0; nl < 8; nl++) mxb[nl] = fmaxf(mxb[nl], __shfl_xor(mxb[nl], s));
  }
  if ((tid & 63) == 0) {
#pragma unroll
    for (int nl = 0; nl < 8; nl++) atomicMax(&bmaxu[nl], __float_as_uint(mxb[nl]));
  }
  __syncthreads();
  if (k < KM) {
#pragma unroll
    for (int nl = 0; nl < 8; nl++) {
      float bmax = fmaxf(__uint_as_float(bmaxu[nl]), 1e-30f);
      float xmax = xmaxs[nl];
      unsigned short* Au = A2 + (size_t)(n0 + nl) * RSA;
      unsigned char* rb = Bq + (size_t)(n0 + nl) * RSB;
      Au[k] = f2bfr(aa[nl]);
      rb[k] = (unsigned char)(signed char)lrintf(bb[nl] * (127.f / bmax));
      if (k < 20) {
        ((float*)(Au + 208))[k] = xv[nl][k];
        ((__half*)(rb + 208))[k] = __float2half(xv[nl][k] * (32768.f / xmax));
      }
      if (k == 0) {
        ((float*)(rb + 248))[0] = bmax / 127.f;
        ((float*)(rb + 248))[1] = xmax / 32768.f;
      }
    }
  }
}

// afp20: after a hidden edge (gd 20-channel bf16). Same 3 phases, CIN=20.
__global__ void __launch_bounds__(256) afp20_kernel(
    const unsigned short* __restrict__ gd, const int* __restrict__ off,
    const float* __restrict__ xrp,
    const float* __restrict__ W1, const float* __restrict__ b1,
    const float* __restrict__ W2, const float* __restrict__ b2,
    const float* __restrict__ Wm1n, const float* __restrict__ bm1n,
    unsigned short* __restrict__ A2, unsigned char* __restrict__ Bq,
    float* __restrict__ xrn) {
  __shared__ float ag[8][21], xp[8][21], xv[8][21], degs[8];
  __shared__ unsigned bmaxu[8];
  __shared__ float xmaxs[8];
  int tid = threadIdx.x;
  int n0 = blockIdx.x * 8;
  if (tid < 8) bmaxu[tid] = 0;
  if (tid < 160) {
    int c = tid >> 3, nl = tid & 7;
    int n = n0 + nl;
    int s = off[n], t = off[n + 1];
    ag[nl][c] = seg_sum_bf16(gd + (size_t)c * E_EDGES, s, t);
    xp[nl][c] = xrp[n * 20 + c];
    if (c == 0) degs[nl] = (float)(t - s);
  }
  __syncthreads();
  if (tid < 160) {
    int o = tid >> 3, nl = tid & 7;
    float v = b1[o] + degs[nl] * b2[o];
#pragma unroll
    for (int c = 0; c < 20; c++) {
      v += ag[nl][c] * W2[c * 20 + o] + xp[nl][c] * W1[c * 20 + o];
    }
    float r = fmaxf(v, 0.f);
    xv[nl][o] = r;
    xrn[(n0 + nl) * 20 + o] = r;
  }
  __syncthreads();
  if (tid < 8) {
    float m = 0.f;
#pragma unroll
    for (int c = 0; c < 20; c++) m = fmaxf(m, xv[tid][c]);
    xmaxs[tid] = fmaxf(m, 1e-30f);
  }
  int k = tid;
  float aa[8], bb[8];
  if (k < KM) {
    v2f wab[20];
    float bm = bm1n[k];
#pragma unroll
    for (int c = 0; c < 20; c++) {
      wab[c].x = Wm1n[c * KM + k];
      wab[c].y = Wm1n[(20 + c) * KM + k];
    }
#pragma unroll
    for (int nl = 0; nl < 8; nl++) {
      v2f acc;
      acc.x = bm;
      acc.y = 0.f;
#pragma unroll
      for (int c = 0; c < 20; c++) {
        v2f xc;
        xc.x = xv[nl][c];
        xc.y = xv[nl][c];
        acc += xc * wab[c];
      }
      aa[nl] = acc.x;
      bb[nl] = acc.y;
    }
  }
  float mxb[8];
#pragma unroll
  for (int nl = 0; nl < 8; nl++) mxb[nl] = (k < KM) ? fabsf(bb[nl]) : 0.f;
#pragma unroll
  for (int s = 1; s < 64; s <<= 1) {
#pragma unroll
    for (int nl = 0; nl < 8; nl++) mxb[nl] = fmaxf(mxb[nl], __shfl_xor(mxb[nl], s));
  }
  if ((tid & 63) == 0) {
#pragma unroll
    for (int nl = 0; nl < 8; nl++) atomicMax(&bmaxu[nl], __float_as_uint(mxb[nl]));
  }
  __syncthreads();
  if (k < KM) {
#pragma unroll
    for (int nl = 0; nl < 8; nl++) {
      float bmax = fmaxf(__uint_as_float(bmaxu[nl]), 1e-30f);
      float xmax = xmaxs[nl];
      unsigned short* Au = A2 + (size_t)(n0 + nl) * RSA;
      unsigned char* rb = Bq + (size_t)(n0 + nl) * RSB;
      Au[k] = f2bfr(aa[nl]);
      rb[k] = (unsigned char)(signed char)lrintf(bb[nl] * (127.f / bmax));
      if (k < 20) {
        ((float*)(Au + 208))[k] = xv[nl][k];
        ((__half*)(rb + 208))[k] = __float2half(xv[nl][k] * (32768.f / xmax));
      }
      if (k == 0) {
        ((float*)(rb + 248))[0] = bmax / 127.f;
        ((float*)(rb + 248))[1] = xmax / 32768.f;
      }
    }
  }
}

// ---------------- launch ----------------

extern "C" void kernel_launch(void* const* d_in, const int* in_sizes, int n_in,
                              void* d_out, int out_size, void* d_ws, size_t ws_size,
                              hipStream_t stream) {
  const float* features = (const float*)d_in[0];
  const int* edges = (const int*)d_in[1];
  // d_in[2] = weights (unused by reference)

  const float *dW1 = (const float*)d_in[3], *db1 = (const float*)d_in[4],
              *dWm1 = (const float*)d_in[5], *dbm1 = (const float*)d_in[6],
              *dWm2 = (const float*)d_in[7], *dbm2 = (const float*)d_in[8],
              *dW2 = (const float*)d_in[9], *db2 = (const float*)d_in[10];
  const float *hW1 = (const float*)d_in[11], *hb1 = (const float*)d_in[12],
              *hWm1 = (const float*)d_in[13], *hbm1 = (const float*)d_in[14],
              *hWm2 = (const float*)d_in[15], *hbm2 = (const float*)d_in[16],
              *hW2 = (const float*)d_in[17], *hb2 = (const float*)d_in[18];
  const float *oW1 = (const float*)d_in[19], *ob1 = (const float*)d_in[20],
              *oWm1 = (const float*)d_in[21], *obm1 = (const float*)d_in[22],
              *oWm2 = (const float*)d_in[23], *obm2 = (const float*)d_in[24],
              *oW2 = (const float*)d_in[25], *ob2 = (const float*)d_in[26];

  // workspace layout (float units)
  float* fws = (float*)d_ws;
  size_t o = 0;
  unsigned short* A2 = (unsigned short*)(fws + o); o += (size_t)N_NODES * (RSA / 2);  // 512 B rows
  unsigned char* Bq = (unsigned char*)(fws + o);   o += (size_t)N_NODES * RSB / 4;
  unsigned short* gd = (unsigned short*)(fws + o); o += (size_t)20 * E_EDGES / 2;  // bf16
  float* xrA = fws + o;                            o += (size_t)N_NODES * 20;
  float* xrB = fws + o;                            o += (size_t)N_NODES * 20;
  int* ip = (int*)(fws + o);
  int* hist = ip;   ip += N_NODES;
  int* off = ip;    ip += N_NODES + 4;
  int* cursor = ip; ip += N_NODES;
  int2* se = (int2*)ip;

  const int B256 = 256;
  const int EDGE_G = E_EDGES / 128;  // 3125, exact
  const int NODE8_G = N_NODES / 8;   // 3125, exact

  // build dst-sorted edge list + CSR offsets (recomputed every launch)
  (void)hipMemsetAsync(hist, 0, N_NODES * sizeof(int), stream);
  hist_kernel<<<(E_EDGES + B256 - 1) / B256, B256, 0, stream>>>(edges, hist);
  scan_kernel<<<1, 1024, 0, stream>>>(hist, off, cursor);

  // layer d: 1 -> 20 (scatter + d_out zeroing fused into prep)
  scatter_prep_d_kernel<<<NODE8_G, B256, 0, stream>>>(edges, cursor, se, features,
                                                      dWm1, dbm1, A2, Bq, xrA,
                                                      (float*)d_out);
  edge_kernel<1><<<EDGE_G, 128, 0, stream>>>(se, A2, Bq, dWm2, dbm2, gd);
  afp1_kernel<<<NODE8_G, B256, 0, stream>>>(gd, off, xrA, dW1, db1, dW2, db2,
                                            hWm1, hbm1, A2, Bq, xrB);

  // hidden1
  edge_kernel<20><<<EDGE_G, 128, 0, stream>>>(se, A2, Bq, hWm2, hbm2, gd);
  afp20_kernel<<<NODE8_G, B256, 0, stream>>>(gd, off, xrB, hW1, hb1, hW2, hb2,
                                             hWm1, hbm1, A2, Bq, xrA);
  // hidden2
  edge_kernel<20><<<EDGE_G, 128, 0, stream>>>(se, A2, Bq, hWm2, hbm2, gd);
  afp20_kernel<<<NODE8_G, B256, 0, stream>>>(gd, off, xrA, hW1, hb1, hW2, hb2,
                                             hWm1, hbm1, A2, Bq, xrB);
  // hidden3 -> preps output layer (oWm1)
  edge_kernel<20><<<EDGE_G, 128, 0, stream>>>(se, A2, Bq, hWm2, hbm2, gd);
  afp20_kernel<<<NODE8_G, B256, 0, stream>>>(gd, off, xrB, hW1, hb1, hW2, hb2,
                                             oWm1, obm1, A2, Bq, xrA);
  // output layer: 20 -> 1, gd-free (scalar atomics into d_out) + node terms fused
  edge_final_kernel<<<EDGE_G, 128, 0, stream>>>(se, A2, Bq, oWm2, obm2, oW2,
                                                off, xrA, oW1, ob1, ob2,
                                                (float*)d_out);
}

// Round 3
// 554.316 us; speedup vs baseline: 1.7279x; 1.7279x over previous
//
#include <hip/hip_runtime.h>
#include <hip/hip_fp16.h>

#define N_NODES 25000   // = 3125 * 8 exactly
#define E_EDGES 400000
#define KM 200      // message channels
#define RSA 256     // A-row stride in USHORTS: 200 bf16 A | pad | 20 fp32 x @u208 (512 B row)
#define RSB 256     // B-row stride BYTES: 200 int8 | pad | 20 fp16 x @208 | inv_p,inv_x @248

typedef float v2f __attribute__((ext_vector_type(2)));  // v_pk_fma_f32 operand

__device__ __forceinline__ float2 h2f(unsigned u) {
  return __half22float2(*(const __half2*)&u);
}
__device__ __forceinline__ float4 i8x4f(unsigned u) {
  float4 f;
  f.x = (float)((int)(u << 24) >> 24);
  f.y = (float)((int)(u << 16) >> 24);
  f.z = (float)((int)(u << 8) >> 24);
  f.w = (float)((int)u >> 24);
  return f;
}
// bf16 round-half-up pack / unpack
__device__ __forceinline__ unsigned short f2bfr(float v) {
  unsigned u = __float_as_uint(v) + 0x8000u;
  return (unsigned short)(u >> 16);
}
__device__ __forceinline__ float bf2f(unsigned short h) {
  return __uint_as_float((unsigned)h << 16);
}
// unpack 8 bf16 (one uint4) -> 8 f32: lo half = u<<16, hi half = u&0xffff0000
__device__ __forceinline__ void bf8x(uint4 u, float* h) {
  h[0] = __uint_as_float(u.x << 16);
  h[1] = __uint_as_float(u.x & 0xffff0000u);
  h[2] = __uint_as_float(u.y << 16);
  h[3] = __uint_as_float(u.y & 0xffff0000u);
  h[4] = __uint_as_float(u.z << 16);
  h[5] = __uint_as_float(u.z & 0xffff0000u);
  h[6] = __uint_as_float(u.w << 16);
  h[7] = __uint_as_float(u.w & 0xffff0000u);
}

// Segment sum with batched loads: bitwise-identical to the naive loop.
__device__ __forceinline__ float seg_sum_bf16(const unsigned short* __restrict__ g,
                                              int s, int t) {
  float v = 0.f;
  int e = s;
  int t8 = s + ((t - s) & ~7);
  for (; e < t8; e += 8) {
    unsigned short u0 = g[e + 0], u1 = g[e + 1], u2 = g[e + 2], u3 = g[e + 3];
    unsigned short u4 = g[e + 4], u5 = g[e + 5], u6 = g[e + 6], u7 = g[e + 7];
    v += bf2f(u0); v += bf2f(u1); v += bf2f(u2); v += bf2f(u3);
    v += bf2f(u4); v += bf2f(u5); v += bf2f(u6); v += bf2f(u7);
  }
  int t2 = s + ((t - s) & ~1);
  for (; e < t2; e += 2) {
    unsigned short u0 = g[e + 0], u1 = g[e + 1];
    v += bf2f(u0); v += bf2f(u1);
  }
  if (e < t) v += bf2f(g[e]);
  return v;
}

// ---------------- sort-by-dst (CSR build) ----------------

__global__ void hist_kernel(const int* __restrict__ edges, int* __restrict__ hist) {
  int e = blockIdx.x * blockDim.x + threadIdx.x;
  if (e < E_EDGES) atomicAdd(&hist[edges[E_EDGES + e]], 1);
}

__global__ void scan_kernel(const int* __restrict__ hist, int* __restrict__ off,
                            int* __restrict__ cursor) {
  __shared__ int sums[1024];
  const int CH = (N_NODES + 1023) / 1024;  // 25
  int tid = threadIdx.x;
  int base = tid * CH;
  int s = 0;
  for (int i = 0; i < CH; i++) {
    int idx = base + i;
    if (idx < N_NODES) s += hist[idx];
  }
  sums[tid] = s;
  __syncthreads();
  for (int d = 1; d < 1024; d <<= 1) {
    int v = (tid >= d) ? sums[tid - d] : 0;
    __syncthreads();
    sums[tid] += v;
    __syncthreads();
  }
  int run = (tid == 0) ? 0 : sums[tid - 1];
  for (int i = 0; i < CH; i++) {
    int idx = base + i;
    if (idx < N_NODES) {
      off[idx] = run;
      cursor[idx] = run;
      run += hist[idx];
    }
  }
  if (tid == 1023) off[N_NODES] = run;  // == E
}

// ---------------- per-layer kernels ----------------

// Fused: scatter (128 edges/block) + prep layer-d (8 nodes/block) + d_out zeroing.
// A-panel bf16 (halves gather bytes); x-tail fp32 at ushort offset 208.
__global__ void __launch_bounds__(256) scatter_prep_d_kernel(
    const int* __restrict__ edges, int* __restrict__ cursor, int2* __restrict__ se,
    const float* __restrict__ xin,
    const float* __restrict__ Wm1, const float* __restrict__ bm1,
    unsigned short* __restrict__ A2, unsigned char* __restrict__ Bq,
    float* __restrict__ xr, float* __restrict__ out) {
  int tid = threadIdx.x;
  if (tid < 8) out[blockIdx.x * 8 + tid] = 0.f;
  if (tid < 128) {
    int e = blockIdx.x * 128 + tid;
    int s = edges[e];
    int d = edges[E_EDGES + e];
    int pos = atomicAdd(&cursor[d], 1);
    se[pos] = make_int2(s, d);
  }
  __shared__ unsigned wbmaxu;
  if (tid == 0) wbmaxu = 0;
  __syncthreads();
  int k = tid;
  float wa = 0.f, wb = 0.f, bm = 0.f;
  if (k < KM) {
    bm = bm1[k];
    wa = Wm1[k];
    wb = Wm1[KM + k];
  }
  float mb = (k < KM) ? fabsf(wb) : 0.f;
#pragma unroll
  for (int s = 1; s < 64; s <<= 1) mb = fmaxf(mb, __shfl_xor(mb, s));
  if ((k & 63) == 0) atomicMax(&wbmaxu, __float_as_uint(mb));
  __syncthreads();
  float wbmax = fmaxf(__uint_as_float(wbmaxu), 1e-30f);
  int n0 = blockIdx.x * 8;
  for (int i = 0; i < 8; i++) {
    int n = n0 + i;
    float xv = xin[n];
    float bBound = fmaxf(fabsf(xv) * wbmax, 1e-30f);
    float xBound = fmaxf(fabsf(xv), 1e-30f);
    size_t rowA = (size_t)n * RSA;
    unsigned char* rb = Bq + (size_t)n * RSB;
    if (k == 0) {
      xr[n] = xv;
      ((float*)(A2 + rowA + 208))[0] = xv;
      ((__half*)(rb + 208))[0] = __float2half(xv * (32768.f / xBound));
      ((float*)(rb + 248))[0] = bBound / 127.f;
      ((float*)(rb + 248))[1] = xBound / 32768.f;
    }
    if (k < KM) {
      A2[rowA + k] = f2bfr(bm + xv * wa);
      rb[k] = (unsigned char)(signed char)lrintf(xv * wb * (127.f / bBound));
    }
  }
}

// Edge kernel (R18 loop shape restored — 16-k tiles, unroll 2, loads inline,
// low VGPR, occupancy-driven latency hiding). A-panel bf16: 2 uint4 loads per
// 16-k tile instead of 4 float4 — half the A gather instructions/bytes.
template <int CIN>
__global__ void __launch_bounds__(128) edge_kernel(
    const int2* __restrict__ se,
    const unsigned short* __restrict__ A2, const unsigned char* __restrict__ Bq,
    const float* __restrict__ Wm2, const float* __restrict__ bm2,
    unsigned short* __restrict__ gd) {
  int e = blockIdx.x * 128 + threadIdx.x;  // grid exact: no bounds check
  int2 sd = se[e];
  int src = sd.x;
  int dst = sd.y;
  const unsigned short* Ar = A2 + (size_t)dst * RSA;
  const unsigned char* Br = Bq + (size_t)src * RSB;
  float invB = ((const float*)(Br + 248))[0];
  constexpr int NP = (CIN + 1) / 2;
  v2f gate2[NP];
  if constexpr (CIN == 20) {
#pragma unroll
    for (int i = 0; i < NP; i++) gate2[i] = *(const v2f*)(bm2 + 2 * i);
  } else {
    gate2[0].x = bm2[0];
    gate2[0].y = 0.f;
  }
#pragma unroll 2
  for (int k = 0; k < 192; k += 16) {
    uint4 a01 = *(const uint4*)(Ar + k);       // 8 bf16
    uint4 a23 = *(const uint4*)(Ar + k + 8);   // 8 bf16
    uint4 braw = *(const uint4*)(Br + k);      // 16 int8
    float af[16];
    bf8x(a01, af);
    bf8x(a23, af + 8);
    float4 f0 = i8x4f(braw.x);
    float4 f1 = i8x4f(braw.y);
    float4 f2 = i8x4f(braw.z);
    float4 f3 = i8x4f(braw.w);
    float h[16];
    h[0] = fmaxf(af[0] + f0.x * invB, 0.f);
    h[1] = fmaxf(af[1] + f0.y * invB, 0.f);
    h[2] = fmaxf(af[2] + f0.z * invB, 0.f);
    h[3] = fmaxf(af[3] + f0.w * invB, 0.f);
    h[4] = fmaxf(af[4] + f1.x * invB, 0.f);
    h[5] = fmaxf(af[5] + f1.y * invB, 0.f);
    h[6] = fmaxf(af[6] + f1.z * invB, 0.f);
    h[7] = fmaxf(af[7] + f1.w * invB, 0.f);
    h[8] = fmaxf(af[8] + f2.x * invB, 0.f);
    h[9] = fmaxf(af[9] + f2.y * invB, 0.f);
    h[10] = fmaxf(af[10] + f2.z * invB, 0.f);
    h[11] = fmaxf(af[11] + f2.w * invB, 0.f);
    h[12] = fmaxf(af[12] + f3.x * invB, 0.f);
    h[13] = fmaxf(af[13] + f3.y * invB, 0.f);
    h[14] = fmaxf(af[14] + f3.z * invB, 0.f);
    h[15] = fmaxf(af[15] + f3.w * invB, 0.f);
    if constexpr (CIN == 20) {
#pragma unroll
      for (int j = 0; j < 16; j++) {
        v2f hj;
        hj.x = h[j];
        hj.y = h[j];
        const v2f* w2 = (const v2f*)(Wm2 + (k + j) * 20);
#pragma unroll
        for (int i = 0; i < 10; i++) gate2[i] += hj * w2[i];
      }
    } else {
      float g = gate2[0].x;
#pragma unroll
      for (int j = 0; j < 16; j++) g += h[j] * Wm2[k + j];
      gate2[0].x = g;
    }
  }
  {  // tail k = 192..199
    uint4 a01 = *(const uint4*)(Ar + 192);     // 8 bf16
    uint2 braw = *(const uint2*)(Br + 192);    // 8 int8
    float af[8];
    bf8x(a01, af);
    float4 f01 = i8x4f(braw.x);
    float4 f23 = i8x4f(braw.y);
    float h[8];
    h[0] = fmaxf(af[0] + f01.x * invB, 0.f);
    h[1] = fmaxf(af[1] + f01.y * invB, 0.f);
    h[2] = fmaxf(af[2] + f01.z * invB, 0.f);
    h[3] = fmaxf(af[3] + f01.w * invB, 0.f);
    h[4] = fmaxf(af[4] + f23.x * invB, 0.f);
    h[5] = fmaxf(af[5] + f23.y * invB, 0.f);
    h[6] = fmaxf(af[6] + f23.z * invB, 0.f);
    h[7] = fmaxf(af[7] + f23.w * invB, 0.f);
    if constexpr (CIN == 20) {
#pragma unroll
      for (int j = 0; j < 8; j++) {
        v2f hj;
        hj.x = h[j];
        hj.y = h[j];
        const v2f* w2 = (const v2f*)(Wm2 + (192 + j) * 20);
#pragma unroll
        for (int i = 0; i < 10; i++) gate2[i] += hj * w2[i];
      }
    } else {
      float g = gate2[0].x;
#pragma unroll
      for (int j = 0; j < 8; j++) g += h[j] * Wm2[192 + j];
      gate2[0].x = g;
    }
  }
  // x-diff tails: A-x fp32 @ushort 208, B-x fp16-scaled; coalesced bf16 nt-stores
  float invXb = ((const float*)(Br + 248))[1];
  const __half* xtb = (const __half*)(Br + 208);
  const float* Ax = (const float*)(Ar + 208);
  if constexpr (CIN == 20) {
    unsigned wxb[10];
    {
      uint4 s0 = *(const uint4*)(xtb);
      uint4 s1 = *(const uint4*)(xtb + 8);
      uint2 s2 = *(const uint2*)(xtb + 16);
      wxb[0] = s0.x; wxb[1] = s0.y; wxb[2] = s0.z; wxb[3] = s0.w;
      wxb[4] = s1.x; wxb[5] = s1.y; wxb[6] = s1.z; wxb[7] = s1.w;
      wxb[8] = s2.x; wxb[9] = s2.y;
    }
#pragma unroll
    for (int i = 0; i < 10; i++) {
      float2 xa = *(const float2*)(Ax + 2 * i);
      float2 fb = h2f(wxb[i]);
      int c0 = 2 * i, c1 = 2 * i + 1;
      __builtin_nontemporal_store(f2bfr(gate2[i].x * (xa.x - fb.x * invXb)),
                                  gd + (size_t)c0 * E_EDGES + e);
      __builtin_nontemporal_store(f2bfr(gate2[i].y * (xa.y - fb.y * invXb)),
                                  gd + (size_t)c1 * E_EDGES + e);
    }
  } else {
    float xa = Ax[0];
    float xb = __half2float(xtb[0]) * invXb;
    __builtin_nontemporal_store(f2bfr(gate2[0].x * (xa - xb)), gd + e);
  }
}

// Final-layer edge kernel + node-term fold (same R18 loop shape, bf16 A).
__global__ void __launch_bounds__(128) edge_final_kernel(
    const int2* __restrict__ se,
    const unsigned short* __restrict__ A2, const unsigned char* __restrict__ Bq,
    const float* __restrict__ Wm2, const float* __restrict__ bm2,
    const float* __restrict__ W2,
    const int* __restrict__ off, const float* __restrict__ xrp,
    const float* __restrict__ W1, const float* __restrict__ b1,
    const float* __restrict__ b2, float* __restrict__ out) {
  int e = blockIdx.x * 128 + threadIdx.x;
  int2 sd = se[e];
  int src = sd.x;
  int dst = sd.y;
  const unsigned short* Ar = A2 + (size_t)dst * RSA;
  const unsigned char* Br = Bq + (size_t)src * RSB;
  float invB = ((const float*)(Br + 248))[0];
  v2f gate2[10];
#pragma unroll
  for (int i = 0; i < 10; i++) gate2[i] = *(const v2f*)(bm2 + 2 * i);
#pragma unroll 2
  for (int k = 0; k < 192; k += 16) {
    uint4 a01 = *(const uint4*)(Ar + k);
    uint4 a23 = *(const uint4*)(Ar + k + 8);
    uint4 braw = *(const uint4*)(Br + k);
    float af[16];
    bf8x(a01, af);
    bf8x(a23, af + 8);
    float4 f0 = i8x4f(braw.x);
    float4 f1 = i8x4f(braw.y);
    float4 f2 = i8x4f(braw.z);
    float4 f3 = i8x4f(braw.w);
    float h[16];
    h[0] = fmaxf(af[0] + f0.x * invB, 0.f);
    h[1] = fmaxf(af[1] + f0.y * invB, 0.f);
    h[2] = fmaxf(af[2] + f0.z * invB, 0.f);
    h[3] = fmaxf(af[3] + f0.w * invB, 0.f);
    h[4] = fmaxf(af[4] + f1.x * invB, 0.f);
    h[5] = fmaxf(af[5] + f1.y * invB, 0.f);
    h[6] = fmaxf(af[6] + f1.z * invB, 0.f);
    h[7] = fmaxf(af[7] + f1.w * invB, 0.f);
    h[8] = fmaxf(af[8] + f2.x * invB, 0.f);
    h[9] = fmaxf(af[9] + f2.y * invB, 0.f);
    h[10] = fmaxf(af[10] + f2.z * invB, 0.f);
    h[11] = fmaxf(af[11] + f2.w * invB, 0.f);
    h[12] = fmaxf(af[12] + f3.x * invB, 0.f);
    h[13] = fmaxf(af[13] + f3.y * invB, 0.f);
    h[14] = fmaxf(af[14] + f3.z * invB, 0.f);
    h[15] = fmaxf(af[15] + f3.w * invB, 0.f);
#pragma unroll
    for (int j = 0; j < 16; j++) {
      v2f hj;
      hj.x = h[j];
      hj.y = h[j];
      const v2f* w2 = (const v2f*)(Wm2 + (k + j) * 20);
#pragma unroll
      for (int i = 0; i < 10; i++) gate2[i] += hj * w2[i];
    }
  }
  {  // tail k = 192..199
    uint4 a01 = *(const uint4*)(Ar + 192);
    uint2 braw = *(const uint2*)(Br + 192);
    float af[8];
    bf8x(a01, af);
    float4 f01 = i8x4f(braw.x);
    float4 f23 = i8x4f(braw.y);
    float h[8];
    h[0] = fmaxf(af[0] + f01.x * invB, 0.f);
    h[1] = fmaxf(af[1] + f01.y * invB, 0.f);
    h[2] = fmaxf(af[2] + f01.z * invB, 0.f);
    h[3] = fmaxf(af[3] + f01.w * invB, 0.f);
    h[4] = fmaxf(af[4] + f23.x * invB, 0.f);
    h[5] = fmaxf(af[5] + f23.y * invB, 0.f);
    h[6] = fmaxf(af[6] + f23.z * invB, 0.f);
    h[7] = fmaxf(af[7] + f23.w * invB, 0.f);
#pragma unroll
    for (int j = 0; j < 8; j++) {
      v2f hj;
      hj.x = h[j];
      hj.y = h[j];
      const v2f* w2 = (const v2f*)(Wm2 + (192 + j) * 20);
#pragma unroll
      for (int i = 0; i < 10; i++) gate2[i] += hj * w2[i];
    }
  }
  // scalar edge contribution: dot(gate * xd, W2)
  float invXb = ((const float*)(Br + 248))[1];
  const __half* xtb = (const __half*)(Br + 208);
  const float* Ax = (const float*)(Ar + 208);
  unsigned wxb[10];
  {
    uint4 s0 = *(const uint4*)(xtb);
    uint4 s1 = *(const uint4*)(xtb + 8);
    uint2 s2 = *(const uint2*)(xtb + 16);
    wxb[0] = s0.x; wxb[1] = s0.y; wxb[2] = s0.z; wxb[3] = s0.w;
    wxb[4] = s1.x; wxb[5] = s1.y; wxb[6] = s1.z; wxb[7] = s1.w;
    wxb[8] = s2.x; wxb[9] = s2.y;
  }
  float sv = 0.f;
#pragma unroll
  for (int i = 0; i < 10; i++) {
    float2 xa = *(const float2*)(Ax + 2 * i);
    float2 fb = h2f(wxb[i]);
    sv += gate2[i].x * (xa.x - fb.x * invXb) * W2[2 * i] +
          gate2[i].y * (xa.y - fb.y * invXb) * W2[2 * i + 1];
  }
  // wave-level segmented sum over equal-dst runs (dst-sorted), then 1 atomic/run
  int lane = threadIdx.x & 63;
  bool seg[6];
#pragma unroll
  for (int i = 0; i < 6; i++) {
    int s = 1 << i;
    int od = __shfl_up(dst, s);
    seg[i] = (lane >= s) && (od == dst);
  }
#pragma unroll
  for (int i = 0; i < 6; i++) {
    float o = __shfl_up(sv, 1 << i);
    if (seg[i]) sv += o;
  }
  int dn = __shfl_down(dst, 1);
  bool is_last = (lane == 63) || (dn != dst);
  if (is_last) atomicAdd(out + dst, sv);
  // node-term fold: 8 nodes/block, grid 3125 = N/8
  int tid = threadIdx.x;
  if (tid < 8) {
    int n = blockIdx.x * 8 + tid;
    float deg = (float)(off[n + 1] - off[n]);
    float v = b1[0] + deg * b2[0];
    const float* xp = xrp + (size_t)n * 20;
#pragma unroll
    for (int c = 0; c < 20; c++) v += xp[c] * W1[c];
    atomicAdd(out + n, v);
  }
}

// afp1: after layer-d edge (gd 1-channel bf16). Per block: 8 nodes.
__global__ void __launch_bounds__(256) afp1_kernel(
    const unsigned short* __restrict__ gd, const int* __restrict__ off,
    const float* __restrict__ xrp,
    const float* __restrict__ W1, const float* __restrict__ b1,
    const float* __restrict__ W2, const float* __restrict__ b2,
    const float* __restrict__ Wm1n, const float* __restrict__ bm1n,
    unsigned short* __restrict__ A2, unsigned char* __restrict__ Bq,
    float* __restrict__ xrn) {
  __shared__ float ag[8], xp[8], degs[8];
  __shared__ float xv[8][21];
  __shared__ unsigned bmaxu[8];
  __shared__ float xmaxs[8];
  int tid = threadIdx.x;
  int n0 = blockIdx.x * 8;
  if (tid < 8) {
    bmaxu[tid] = 0;
    int n = n0 + tid;
    int s = off[n], t = off[n + 1];
    ag[tid] = seg_sum_bf16(gd, s, t);
    xp[tid] = xrp[n];
    degs[tid] = (float)(t - s);
  }
  __syncthreads();
  if (tid < 160) {
    int o = tid >> 3, nl = tid & 7;
    float v = b1[o] + degs[nl] * b2[o] + ag[nl] * W2[o] + xp[nl] * W1[o];
    float r = fmaxf(v, 0.f);
    xv[nl][o] = r;
    xrn[(n0 + nl) * 20 + o] = r;
  }
  __syncthreads();
  if (tid < 8) {
    float m = 0.f;
#pragma unroll
    for (int c = 0; c < 20; c++) m = fmaxf(m, xv[tid][c]);
    xmaxs[tid] = fmaxf(m, 1e-30f);
  }
  int k = tid;
  float aa[8], bb[8];
  if (k < KM) {
    v2f wab[20];
    float bm = bm1n[k];
#pragma unroll
    for (int c = 0; c < 20; c++) {
      wab[c].x = Wm1n[c * KM + k];
      wab[c].y = Wm1n[(20 + c) * KM + k];
    }
#pragma unroll
    for (int nl = 0; nl < 8; nl++) {
      v2f acc;
      acc.x = bm;
      acc.y = 0.f;
#pragma unroll
      for (int c = 0; c < 20; c++) {
        v2f xc;
        xc.x = xv[nl][c];
        xc.y = xv[nl][c];
        acc += xc * wab[c];
      }
      aa[nl] = acc.x;
      bb[nl] = acc.y;
    }
  }
  float mxb[8];
#pragma unroll
  for (int nl = 0; nl < 8; nl++) mxb[nl] = (k < KM) ? fabsf(bb[nl]) : 0.f;
#pragma unroll
  for (int s = 1; s < 64; s <<= 1) {
#pragma unroll
    for (int nl = 0; nl < 8; nl++) mxb[nl] = fmaxf(mxb[nl], __shfl_xor(mxb[nl], s));
  }
  if ((tid & 63) == 0) {
#pragma unroll
    for (int nl = 0; nl < 8; nl++) atomicMax(&bmaxu[nl], __float_as_uint(mxb[nl]));
  }
  __syncthreads();
  if (k < KM) {
#pragma unroll
    for (int nl = 0; nl < 8; nl++) {
      float bmax = fmaxf(__uint_as_float(bmaxu[nl]), 1e-30f);
      float xmax = xmaxs[nl];
      unsigned short* Au = A2 + (size_t)(n0 + nl) * RSA;
      unsigned char* rb = Bq + (size_t)(n0 + nl) * RSB;
      Au[k] = f2bfr(aa[nl]);
      rb[k] = (unsigned char)(signed char)lrintf(bb[nl] * (127.f / bmax));
      if (k < 20) {
        ((float*)(Au + 208))[k] = xv[nl][k];
        ((__half*)(rb + 208))[k] = __float2half(xv[nl][k] * (32768.f / xmax));
      }
      if (k == 0) {
        ((float*)(rb + 248))[0] = bmax / 127.f;
        ((float*)(rb + 248))[1] = xmax / 32768.f;
      }
    }
  }
}

// afp20: after a hidden edge (gd 20-channel bf16). Same 3 phases, CIN=20.
__global__ void __launch_bounds__(256) afp20_kernel(
    const unsigned short* __restrict__ gd, const int* __restrict__ off,
    const float* __restrict__ xrp,
    const float* __restrict__ W1, const float* __restrict__ b1,
    const float* __restrict__ W2, const float* __restrict__ b2,
    const float* __restrict__ Wm1n, const float* __restrict__ bm1n,
    unsigned short* __restrict__ A2, unsigned char* __restrict__ Bq,
    float* __restrict__ xrn) {
  __shared__ float ag[8][21], xp[8][21], xv[8][21], degs[8];
  __shared__ unsigned bmaxu[8];
  __shared__ float xmaxs[8];
  int tid = threadIdx.x;
  int n0 = blockIdx.x * 8;
  if (tid < 8) bmaxu[tid] = 0;
  if (tid < 160) {
    int c = tid >> 3, nl = tid & 7;
    int n = n0 + nl;
    int s = off[n], t = off[n + 1];
    ag[nl][c] = seg_sum_bf16(gd + (size_t)c * E_EDGES, s, t);
    xp[nl][c] = xrp[n * 20 + c];
    if (c == 0) degs[nl] = (float)(t - s);
  }
  __syncthreads();
  if (tid < 160) {
    int o = tid >> 3, nl = tid & 7;
    float v = b1[o] + degs[nl] * b2[o];
#pragma unroll
    for (int c = 0; c < 20; c++) {
      v += ag[nl][c] * W2[c * 20 + o] + xp[nl][c] * W1[c * 20 + o];
    }
    float r = fmaxf(v, 0.f);
    xv[nl][o] = r;
    xrn[(n0 + nl) * 20 + o] = r;
  }
  __syncthreads();
  if (tid < 8) {
    float m = 0.f;
#pragma unroll
    for (int c = 0; c < 20; c++) m = fmaxf(m, xv[tid][c]);
    xmaxs[tid] = fmaxf(m, 1e-30f);
  }
  int k = tid;
  float aa[8], bb[8];
  if (k < KM) {
    v2f wab[20];
    float bm = bm1n[k];
#pragma unroll
    for (int c = 0; c < 20; c++) {
      wab[c].x = Wm1n[c * KM + k];
      wab[c].y = Wm1n[(20 + c) * KM + k];
    }
#pragma unroll
    for (int nl = 0; nl < 8; nl++) {
      v2f acc;
      acc.x = bm;
      acc.y = 0.f;
#pragma unroll
      for (int c = 0; c < 20; c++) {
        v2f xc;
        xc.x = xv[nl][c];
        xc.y = xv[nl][c];
        acc += xc * wab[c];
      }
      aa[nl] = acc.x;
      bb[nl] = acc.y;
    }
  }
  float mxb[8];
#pragma unroll
  for (int nl = 0; nl < 8; nl++) mxb[nl] = (k < KM) ? fabsf(bb[nl]) : 0.f;
#pragma unroll
  for (int s = 1; s < 64; s <<= 1) {
#pragma unroll
    for (int nl = 0; nl < 8; nl++) mxb[nl] = fmaxf(mxb[nl], __shfl_xor(mxb[nl], s));
  }
  if ((tid & 63) == 0) {
#pragma unroll
    for (int nl = 0; nl < 8; nl++) atomicMax(&bmaxu[nl], __float_as_uint(mxb[nl]));
  }
  __syncthreads();
  if (k < KM) {
#pragma unroll
    for (int nl = 0; nl < 8; nl++) {
      float bmax = fmaxf(__uint_as_float(bmaxu[nl]), 1e-30f);
      float xmax = xmaxs[nl];
      unsigned short* Au = A2 + (size_t)(n0 + nl) * RSA;
      unsigned char* rb = Bq + (size_t)(n0 + nl) * RSB;
      Au[k] = f2bfr(aa[nl]);
      rb[k] = (unsigned char)(signed char)lrintf(bb[nl] * (127.f / bmax));
      if (k < 20) {
        ((float*)(Au + 208))[k] = xv[nl][k];
        ((__half*)(rb + 208))[k] = __float2half(xv[nl][k] * (32768.f / xmax));
      }
      if (k == 0) {
        ((float*)(rb + 248))[0] = bmax / 127.f;
        ((float*)(rb + 248))[1] = xmax / 32768.f;
      }
    }
  }
}

// ---------------- launch ----------------

extern "C" void kernel_launch(void* const* d_in, const int* in_sizes, int n_in,
                              void* d_out, int out_size, void* d_ws, size_t ws_size,
                              hipStream_t stream) {
  const float* features = (const float*)d_in[0];
  const int* edges = (const int*)d_in[1];
  // d_in[2] = weights (unused by reference)

  const float *dW1 = (const float*)d_in[3], *db1 = (const float*)d_in[4],
              *dWm1 = (const float*)d_in[5], *dbm1 = (const float*)d_in[6],
              *dWm2 = (const float*)d_in[7], *dbm2 = (const float*)d_in[8],
              *dW2 = (const float*)d_in[9], *db2 = (const float*)d_in[10];
  const float *hW1 = (const float*)d_in[11], *hb1 = (const float*)d_in[12],
              *hWm1 = (const float*)d_in[13], *hbm1 = (const float*)d_in[14],
              *hWm2 = (const float*)d_in[15], *hbm2 = (const float*)d_in[16],
              *hW2 = (const float*)d_in[17], *hb2 = (const float*)d_in[18];
  const float *oW1 = (const float*)d_in[19], *ob1 = (const float*)d_in[20],
              *oWm1 = (const float*)d_in[21], *obm1 = (const float*)d_in[22],
              *oWm2 = (const float*)d_in[23], *obm2 = (const float*)d_in[24],
              *oW2 = (const float*)d_in[25], *ob2 = (const float*)d_in[26];

  // workspace layout (float units)
  float* fws = (float*)d_ws;
  size_t o = 0;
  unsigned short* A2 = (unsigned short*)(fws + o); o += (size_t)N_NODES * (RSA / 2);  // 512 B rows
  unsigned char* Bq = (unsigned char*)(fws + o);   o += (size_t)N_NODES * RSB / 4;
  unsigned short* gd = (unsigned short*)(fws + o); o += (size_t)20 * E_EDGES / 2;  // bf16
  float* xrA = fws + o;                            o += (size_t)N_NODES * 20;
  float* xrB = fws + o;                            o += (size_t)N_NODES * 20;
  int* ip = (int*)(fws + o);
  int* hist = ip;   ip += N_NODES;
  int* off = ip;    ip += N_NODES + 4;
  int* cursor = ip; ip += N_NODES;
  int2* se = (int2*)ip;

  const int B256 = 256;
  const int EDGE_G = E_EDGES / 128;  // 3125, exact
  const int NODE8_G = N_NODES / 8;   // 3125, exact

  // build dst-sorted edge list + CSR offsets (recomputed every launch)
  (void)hipMemsetAsync(hist, 0, N_NODES * sizeof(int), stream);
  hist_kernel<<<(E_EDGES + B256 - 1) / B256, B256, 0, stream>>>(edges, hist);
  scan_kernel<<<1, 1024, 0, stream>>>(hist, off, cursor);

  // layer d: 1 -> 20 (scatter + d_out zeroing fused into prep)
  scatter_prep_d_kernel<<<NODE8_G, B256, 0, stream>>>(edges, cursor, se, features,
                                                      dWm1, dbm1, A2, Bq, xrA,
                                                      (float*)d_out);
  edge_kernel<1><<<EDGE_G, 128, 0, stream>>>(se, A2, Bq, dWm2, dbm2, gd);
  afp1_kernel<<<NODE8_G, B256, 0, stream>>>(gd, off, xrA, dW1, db1, dW2, db2,
                                            hWm1, hbm1, A2, Bq, xrB);

  // hidden1
  edge_kernel<20><<<EDGE_G, 128, 0, stream>>>(se, A2, Bq, hWm2, hbm2, gd);
  afp20_kernel<<<NODE8_G, B256, 0, stream>>>(gd, off, xrB, hW1, hb1, hW2, hb2,
                                             hWm1, hbm1, A2, Bq, xrA);
  // hidden2
  edge_kernel<20><<<EDGE_G, 128, 0, stream>>>(se, A2, Bq, hWm2, hbm2, gd);
  afp20_kernel<<<NODE8_G, B256, 0, stream>>>(gd, off, xrA, hW1, hb1, hW2, hb2,
                                             hWm1, hbm1, A2, Bq, xrB);
  // hidden3 -> preps output layer (oWm1)
  edge_kernel<20><<<EDGE_G, 128, 0, stream>>>(se, A2, Bq, hWm2, hbm2, gd);
  afp20_kernel<<<NODE8_G, B256, 0, stream>>>(gd, off, xrB, hW1, hb1, hW2, hb2,
                                             oWm1, obm1, A2, Bq, xrA);
  // output layer: 20 -> 1, gd-free (scalar atomics into d_out) + node terms fused
  edge_final_kernel<<<EDGE_G, 128, 0, stream>>>(se, A2, Bq, oWm2, obm2, oW2,
                                                off, xrA, oW1, ob1, ob2,
                                                (float*)d_out);
}